// Round 14
// baseline (6078.947 us; speedup 1.0000x reference)
//
#include <hip/hip_runtime.h>

// VanillaRNN: BATCH=1024, SEQ=512, HID=512, OUT=10
// h <- tanh(W_hh @ h + W_hx x_t + b_h), 512 steps, then y = W_yh h + b_y.
//
// Round 18 = Round 17 resubmitted (container failed twice = infra flake;
// kernel has no spin/coop/atomic constructs; bf-ring + self-prefetch
// re-audited correct -- self-prefetch reads only the wave's OWN writes,
// DS ops are wave-ordered, so it is barrier-independent).
// Design: R13 champion (1208us) + per-wave rotated kk order, kk=(2w+t)&15:
//   * CU-level DS duty flat: exactly 2 of 8 waves in a 5-read LDS-W chunk
//     at any t (R13: all 8 simultaneously -> bursts).
//   * SIMD partners (w, w+4) offset by 8 slots: one stalls on DS while the
//     other is in the MFMA-dense Wr region.
//   * wave w's first two chunks are its OWN h-blocks (2w, 2w+1) -> their
//     ds_reads issue BEFORE barrier-2 and complete during the drain ->
//     bf ring (2 slots, 8 regs) runs depth-2 from the first chunk.
// Builtin MFMAs only. Gates: WRITE_SIZE 1024KB, absmax pass.
//
// ws: [0,1MB) hG (final h, frag-blocked) | [2MB,2.5MB) W A-frags.

#define BATCH 1024
#define SEQT  512
#define HID   512
#define OUTD  10
#define KR    12   // kk-blocks (of K=32) in registers: K=384
#define NKK   16

typedef _Float16 f16;
typedef _Float16 f16x8 __attribute__((ext_vector_type(8)));
typedef _Float16 f16x4 __attribute__((ext_vector_type(4)));
typedef float    f32x4 __attribute__((ext_vector_type(4)));

// W_hh fp32 [H][H] -> fp16 A-fragment layout:
// entry ((g*4+mt)*16+kk)*64+lane = f16x8 of A[m][k],
// m = g*64+mt*16+(lane&15), k = kk*32+((lane>>4)&3)*8+j.
__global__ void wconv_kernel(const float* __restrict__ Whh, f16* __restrict__ frag) {
    int id = blockIdx.x * blockDim.x + threadIdx.x;   // 0..32767
    int lane = id & 63;
    int kk   = (id >> 6) & 15;
    int mt   = (id >> 10) & 3;
    int g    = id >> 12;
    int m = g * 64 + mt * 16 + (lane & 15);
    int k = kk * 32 + ((lane >> 4) & 3) * 8;
    const float* src = Whh + (size_t)m * HID + k;
    f16x8 v;
#pragma unroll
    for (int j = 0; j < 8; ++j) v[j] = (f16)src[j];
    *(f16x8*)(frag + (size_t)id * 8) = v;
}

__device__ __forceinline__ float fast_tanh(float v) {
    v = fminf(fmaxf(v, -15.f), 15.f);
    float e = __expf(2.f * v);
    return (e - 1.f) * __builtin_amdgcn_rcpf(e + 1.f);
}

__global__ __launch_bounds__(512)
__attribute__((amdgpu_waves_per_eu(2, 2)))
void rnn_cu(
    const f16* __restrict__ frag,   // W_hh A-frags (all 16 kk-blocks)
    f16* __restrict__ hG,           // final h, frag-blocked [64][16][64][8]
    const float* __restrict__ x,    // [B][T]
    const float* __restrict__ Whx,  // [H]
    const float* __restrict__ bh)   // [H]
{
    // HB first: its ds offsets (<16 KB) fit the 16-bit imm with lane-only base.
    __shared__ f16 HB[8192];                    // h, B-frag layout, 16 KB
    __shared__ f16 WL[65536];                   // W A-frags kk 12..15, 128 KB

    const int tid  = threadIdx.x;
    const int w    = tid >> 6;       // wave = row-group of 64 rows
    const int lane = tid & 63;
    const int n    = lane & 15;      // batch col within group
    const int q    = lane >> 4;
    const int bg   = blockIdx.x;     // batch group: cols [bg*16, +16)
    const int w2   = w * 2;

    // ---- h(0) = 0 ----
    {
        f16x8 z;
#pragma unroll
        for (int j = 0; j < 8; ++j) z[j] = (f16)0.f;
        *(f16x8*)&HB[tid * 16]     = z;
        *(f16x8*)&HB[tid * 16 + 8] = z;
    }

    const f16x8* A = (const f16x8*)frag;

    // ---- LDS W portion: wave w stages its (mt, kk 12..15) frags ----
#pragma unroll
    for (int mt = 0; mt < 4; ++mt)
#pragma unroll
        for (int kkl = 0; kkl < 4; ++kkl) {
            int e = ((w * 4 + mt) * 4 + kkl) * 64 + lane;
            *(f16x8*)&WL[e * 8] = A[((w * 4 + mt) * 16 + (KR + kkl)) * 64 + lane];
        }

    // ---- register W portion: kk 0..11, kk-major, static indices ----
    f16x8 Wr[KR * 4];
#pragma unroll
    for (int kk = 0; kk < KR; ++kk)
#pragma unroll
        for (int mt = 0; mt < 4; ++mt)
            Wr[kk * 4 + mt] = A[((w * 4 + mt) * 16 + kk) * 64 + lane];

    __syncthreads();

    const int b = bg * 16 + n;
    const float* xp = x + (size_t)b * SEQT;

    // ---- bf ring: preload own 2 blocks (h(0), just zeroed) ----
    f16x8 bfr[2];
    bfr[0] = *(const f16x8*)&HB[(w2 * 64 + lane) * 8];
    bfr[1] = *(const f16x8*)&HB[((w2 + 1) * 64 + lane) * 8];

#pragma unroll 1
    for (int s = 0; s < SEQT; ++s) {
        float xv = xp[s];

        f32x4 acc[4] = {{0,0,0,0},{0,0,0,0},{0,0,0,0},{0,0,0,0}};

        // ---- rotated schedule, depth-2 bf ring ----
        // kk_t = (2w + t) & 15; slots t=0,1 preloaded (own blocks).
#pragma unroll
        for (int t = 0; t < NKK; ++t) {
            const f16x8 bf = bfr[t & 1];
            if (t + 2 < NKK) {   // refill slot with block t+2 (depth-2)
                const int kn = (w2 + t + 2) & 15;
                bfr[t & 1] = *(const f16x8*)&HB[(kn * 64 + lane) * 8];
            }
            const int kb = (w2 + t) & 15;
            if (kb >= KR) {              // LDS-W chunk (4 frags from WL)
                const int kkl = kb - KR;
#pragma unroll
                for (int mt = 0; mt < 4; ++mt) {
                    f16x8 a = *(const f16x8*)&WL[(((w * 4 + mt) * 4 + kkl) * 64 + lane) * 8];
                    acc[mt] = __builtin_amdgcn_mfma_f32_16x16x32_f16(
                        a, bf, acc[mt], 0, 0, 0);
                }
            } else {                     // register-W chunk
#pragma unroll
                for (int mt = 0; mt < 4; ++mt)
                    acc[mt] = __builtin_amdgcn_mfma_f32_16x16x32_f16(
                        Wr[kb * 4 + mt], bf, acc[mt], 0, 0, 0);
            }
        }

        __syncthreads();   // all reads of h(s) done before in-place overwrite

        // Whx/bh in-loop (anti-LICM: hoisting costs 32 regs -> spill).
        const float* wbp = Whx;
        const float* bbp = bh;
        asm volatile("" : "+v"(wbp), "+v"(bbp));

        // ---- epilogue: tanh, write h(s+1) in B-frag layout ----
        // C layout: col n = lane&15, row m = w*64 + mt*16 + q*4 + r.
#pragma unroll
        for (int mt = 0; mt < 4; ++mt) {
            int m0 = w * 64 + mt * 16 + q * 4;
            f32x4 whx4 = *(const f32x4*)(wbp + m0);
            f32x4 bh4  = *(const f32x4*)(bbp + m0);
            f16x4 hv;
#pragma unroll
            for (int r = 0; r < 4; ++r) {
                float pre = acc[mt][r] + whx4[r] * xv + bh4[r];
                hv[r] = (f16)fast_tanh(pre);
            }
            int kkd = w2 + (mt >> 1);
            int q2  = (mt & 1) * 2 + (q >> 1);
            int j0  = (q & 1) * 4;
            int off = (kkd * 64 + q2 * 16 + n) * 8 + j0;
            if (s < SEQT - 1) {
                *(f16x4*)&HB[off] = hv;
            } else {
                *(f16x4*)(hG + (size_t)(((bg * 16 + kkd) * 64 + q2 * 16 + n) * 8 + j0)) = hv;
            }
        }

        // ---- cross-barrier self-prefetch: own blocks of h(s+1).
        // Blocks 2w,2w+1 are written ENTIRELY by wave w above; DS ops are
        // wave-ordered, so these reads see those writes regardless of the
        // barrier. They complete during the barrier drain. ----
        if (s < SEQT - 1) {
            bfr[0] = *(const f16x8*)&HB[(w2 * 64 + lane) * 8];
            bfr[1] = *(const f16x8*)&HB[((w2 + 1) * 64 + lane) * 8];
        }

        __syncthreads();   // h(s+1) complete before next step's reads
    }
}

// out[b][o] = by[o] + sum_k Wyh[o][k] * h[b][k], h in frag-blocked layout.
__global__ __launch_bounds__(256) void y_kernel(
    const f16* __restrict__ h, const float* __restrict__ Wyh,
    const float* __restrict__ by, float* __restrict__ out)
{
    int id = blockIdx.x * blockDim.x + threadIdx.x;
    if (id >= BATCH * OUTD) return;
    int b = id / OUTD, o = id % OUTD;
    int bg = b >> 4, n = b & 15;
    const float* wrow = Wyh + (size_t)o * HID;
    float s = by[o];
    for (int kk = 0; kk < 16; ++kk)
#pragma unroll
        for (int q2 = 0; q2 < 4; ++q2) {
            f16x8 hv = *(const f16x8*)(h + (size_t)((bg * 16 + kk) * 64 + q2 * 16 + n) * 8);
            const float* wp = wrow + kk * 32 + q2 * 8;
#pragma unroll
            for (int j = 0; j < 8; ++j) s += wp[j] * (float)hv[j];
        }
    out[id] = s;
}

extern "C" void kernel_launch(void* const* d_in, const int* in_sizes, int n_in,
                              void* d_out, int out_size, void* d_ws, size_t ws_size,
                              hipStream_t stream) {
    const float* x   = (const float*)d_in[0];
    const float* Whx = (const float*)d_in[1];
    const float* Whh = (const float*)d_in[2];
    const float* Wyh = (const float*)d_in[3];
    const float* bh  = (const float*)d_in[4];
    const float* by  = (const float*)d_in[5];
    float* out = (float*)d_out;

    char* ws   = (char*)d_ws;
    f16*  hG   = (f16*)ws;                       // 1 MB
    f16*  frag = (f16*)(ws + (2 << 20));         // 512 KB

    wconv_kernel<<<128, 256, 0, stream>>>(Whh, frag);
    rnn_cu<<<64, 512, 0, stream>>>(frag, hG, x, Whx, bh);
    y_kernel<<<(BATCH * OUTD + 255) / 256, 256, 0, stream>>>(hG, Wyh, by, out);
}

// Round 15
// 1281.724 us; speedup vs baseline: 4.7428x; 4.7428x over previous
//
#include <hip/hip_runtime.h>

// VanillaRNN: BATCH=1024, SEQ=512, HID=512, OUT=10
// h <- tanh(W_hh @ h + W_hx x_t + b_h), 512 steps, then y = W_yh h + b_y.
//
// Round 19: R17/18's 26MB WRITE_SIZE = rule-#20 violation: per-wave kk
// rotation made Wr[] runtime-indexed -> all 184 W-regs demoted to scratch.
// The desync hypothesis itself was never tested. This round implements it
// COMPILE-TIME: two constexpr schedules, selected by one wave-uniform
// branch around two copies of the unrolled chunk loop:
//   waves 0-3: ordA = {12,0,1,2, 13,3,4,5, 14,6,7,8, 15,9,10,11}  (R13)
//   waves 4-7: ordB = ordA <<rot 2 = LDS-W chunks at t=2,6,10,14
// -> every Wr/WL index is a folded constant (R17's bug impossible);
// SIMD partners (w, w+4) complementary: one in a 5-read DS chunk while
// the other is MFMA-dense; instantaneous DS burst width halves.
// Zero new registers; else R13-verbatim (champion, 1208us).
// Gates: WRITE_SIZE 1024KB + FETCH ~3128 (scratch gone); absmax pass.
//
// ws: [0,1MB) hG (final h, frag-blocked) | [2MB,2.5MB) W A-frags.

#define BATCH 1024
#define SEQT  512
#define HID   512
#define OUTD  10
#define KR    12   // kk-blocks (of K=32) in registers: K=384
#define NKK   16

typedef _Float16 f16;
typedef _Float16 f16x8 __attribute__((ext_vector_type(8)));
typedef _Float16 f16x4 __attribute__((ext_vector_type(4)));
typedef float    f32x4 __attribute__((ext_vector_type(4)));

// W_hh fp32 [H][H] -> fp16 A-fragment layout:
// entry ((g*4+mt)*16+kk)*64+lane = f16x8 of A[m][k],
// m = g*64+mt*16+(lane&15), k = kk*32+((lane>>4)&3)*8+j.
__global__ void wconv_kernel(const float* __restrict__ Whh, f16* __restrict__ frag) {
    int id = blockIdx.x * blockDim.x + threadIdx.x;   // 0..32767
    int lane = id & 63;
    int kk   = (id >> 6) & 15;
    int mt   = (id >> 10) & 3;
    int g    = id >> 12;
    int m = g * 64 + mt * 16 + (lane & 15);
    int k = kk * 32 + ((lane >> 4) & 3) * 8;
    const float* src = Whh + (size_t)m * HID + k;
    f16x8 v;
#pragma unroll
    for (int j = 0; j < 8; ++j) v[j] = (f16)src[j];
    *(f16x8*)(frag + (size_t)id * 8) = v;
}

__device__ __forceinline__ float fast_tanh(float v) {
    v = fminf(fmaxf(v, -15.f), 15.f);
    float e = __expf(2.f * v);
    return (e - 1.f) * __builtin_amdgcn_rcpf(e + 1.f);
}

// One K-chunk loop over a COMPILE-TIME schedule array (indices fold after
// unroll -> Wr stays in registers; rule-#20-safe).
#define KLOOP(ORD)                                                            \
    _Pragma("unroll")                                                         \
    for (int t = 0; t < NKK; ++t) {                                           \
        const int kb = ORD[t];                                                \
        f16x8 bf = *(const f16x8*)&HB[(kb * 64 + lane) * 8];                  \
        if (kb >= KR) {                                                       \
            const int kkl = kb - KR;                                          \
            _Pragma("unroll")                                                 \
            for (int mt = 0; mt < 4; ++mt) {                                  \
                f16x8 a = *(const f16x8*)&WL[(((w * 4 + mt) * 4 + kkl) * 64   \
                                              + lane) * 8];                   \
                acc[mt] = __builtin_amdgcn_mfma_f32_16x16x32_f16(             \
                    a, bf, acc[mt], 0, 0, 0);                                 \
            }                                                                 \
        } else {                                                              \
            _Pragma("unroll")                                                 \
            for (int mt = 0; mt < 4; ++mt)                                    \
                acc[mt] = __builtin_amdgcn_mfma_f32_16x16x32_f16(             \
                    Wr[kb * 4 + mt], bf, acc[mt], 0, 0, 0);                   \
        }                                                                     \
    }

__global__ __launch_bounds__(512)
__attribute__((amdgpu_waves_per_eu(2, 2)))
void rnn_cu(
    const f16* __restrict__ frag,   // W_hh A-frags (all 16 kk-blocks)
    f16* __restrict__ hG,           // final h, frag-blocked [64][16][64][8]
    const float* __restrict__ x,    // [B][T]
    const float* __restrict__ Whx,  // [H]
    const float* __restrict__ bh)   // [H]
{
    // HB first: its ds offsets (<16 KB) fit the 16-bit imm with lane-only base.
    __shared__ f16 HB[8192];                    // h, B-frag layout, 16 KB
    __shared__ f16 WL[65536];                   // W A-frags kk 12..15, 128 KB

    const int tid  = threadIdx.x;
    const int w    = tid >> 6;       // wave = row-group of 64 rows
    const int lane = tid & 63;
    const int n    = lane & 15;      // batch col within group
    const int q    = lane >> 4;
    const int bg   = blockIdx.x;     // batch group: cols [bg*16, +16)

    // ---- h(0) = 0 ----
    {
        f16x8 z;
#pragma unroll
        for (int j = 0; j < 8; ++j) z[j] = (f16)0.f;
        *(f16x8*)&HB[tid * 16]     = z;
        *(f16x8*)&HB[tid * 16 + 8] = z;
    }

    const f16x8* A = (const f16x8*)frag;

    // ---- LDS W portion: wave w stages its (mt, kk 12..15) frags ----
#pragma unroll
    for (int mt = 0; mt < 4; ++mt)
#pragma unroll
        for (int kkl = 0; kkl < 4; ++kkl) {
            int e = ((w * 4 + mt) * 4 + kkl) * 64 + lane;
            *(f16x8*)&WL[e * 8] = A[((w * 4 + mt) * 16 + (KR + kkl)) * 64 + lane];
        }

    // ---- register W portion: kk 0..11, kk-major, static indices ----
    f16x8 Wr[KR * 4];
#pragma unroll
    for (int kk = 0; kk < KR; ++kk)
#pragma unroll
        for (int mt = 0; mt < 4; ++mt)
            Wr[kk * 4 + mt] = A[((w * 4 + mt) * 16 + kk) * 64 + lane];

    __syncthreads();

    const int b = bg * 16 + n;
    const float* xp = x + (size_t)b * SEQT;

    // Two constexpr schedules: LDS-W chunks at t=0,4,8,12 (A) vs t=2,6,10,14
    // (B). Wave-uniform selection; both bodies fully static after unroll.
    static constexpr int ordA[NKK] = {12, 0, 1, 2, 13, 3, 4, 5,
                                      14, 6, 7, 8, 15, 9, 10, 11};
    static constexpr int ordB[NKK] = {1, 2, 13, 3, 4, 5, 14, 6,
                                      7, 8, 15, 9, 10, 11, 12, 0};
    const bool phaseB = ((w >> 2) & 1) != 0;   // waves 4..7

#pragma unroll 1
    for (int s = 0; s < SEQT; ++s) {
        float xv = xp[s];

        f32x4 acc[4] = {{0,0,0,0},{0,0,0,0},{0,0,0,0},{0,0,0,0}};

        if (!phaseB) { KLOOP(ordA) } else { KLOOP(ordB) }

        __syncthreads();   // all reads of h(s) done before in-place overwrite

        // Whx/bh in-loop (anti-LICM: hoisting costs 32 regs -> spill).
        const float* wbp = Whx;
        const float* bbp = bh;
        asm volatile("" : "+v"(wbp), "+v"(bbp));

        // ---- epilogue: tanh, write h(s+1) in B-frag layout ----
        // C layout: col n = lane&15, row m = w*64 + mt*16 + q*4 + r.
#pragma unroll
        for (int mt = 0; mt < 4; ++mt) {
            int m0 = w * 64 + mt * 16 + q * 4;
            f32x4 whx4 = *(const f32x4*)(wbp + m0);
            f32x4 bh4  = *(const f32x4*)(bbp + m0);
            f16x4 hv;
#pragma unroll
            for (int r = 0; r < 4; ++r) {
                float pre = acc[mt][r] + whx4[r] * xv + bh4[r];
                hv[r] = (f16)fast_tanh(pre);
            }
            int kkd = w * 2 + (mt >> 1);
            int q2  = (mt & 1) * 2 + (q >> 1);
            int j0  = (q & 1) * 4;
            int off = (kkd * 64 + q2 * 16 + n) * 8 + j0;
            if (s < SEQT - 1) {
                *(f16x4*)&HB[off] = hv;
            } else {
                *(f16x4*)(hG + (size_t)(((bg * 16 + kkd) * 64 + q2 * 16 + n) * 8 + j0)) = hv;
            }
        }

        __syncthreads();   // h(s+1) complete before next step's reads
    }
}

// out[b][o] = by[o] + sum_k Wyh[o][k] * h[b][k], h in frag-blocked layout.
__global__ __launch_bounds__(256) void y_kernel(
    const f16* __restrict__ h, const float* __restrict__ Wyh,
    const float* __restrict__ by, float* __restrict__ out)
{
    int id = blockIdx.x * blockDim.x + threadIdx.x;
    if (id >= BATCH * OUTD) return;
    int b = id / OUTD, o = id % OUTD;
    int bg = b >> 4, n = b & 15;
    const float* wrow = Wyh + (size_t)o * HID;
    float s = by[o];
    for (int kk = 0; kk < 16; ++kk)
#pragma unroll
        for (int q2 = 0; q2 < 4; ++q2) {
            f16x8 hv = *(const f16x8*)(h + (size_t)((bg * 16 + kk) * 64 + q2 * 16 + n) * 8);
            const float* wp = wrow + kk * 32 + q2 * 8;
#pragma unroll
            for (int j = 0; j < 8; ++j) s += wp[j] * (float)hv[j];
        }
    out[id] = s;
}

extern "C" void kernel_launch(void* const* d_in, const int* in_sizes, int n_in,
                              void* d_out, int out_size, void* d_ws, size_t ws_size,
                              hipStream_t stream) {
    const float* x   = (const float*)d_in[0];
    const float* Whx = (const float*)d_in[1];
    const float* Whh = (const float*)d_in[2];
    const float* Wyh = (const float*)d_in[3];
    const float* bh  = (const float*)d_in[4];
    const float* by  = (const float*)d_in[5];
    float* out = (float*)d_out;

    char* ws   = (char*)d_ws;
    f16*  hG   = (f16*)ws;                       // 1 MB
    f16*  frag = (f16*)(ws + (2 << 20));         // 512 KB

    wconv_kernel<<<128, 256, 0, stream>>>(Whh, frag);
    rnn_cu<<<64, 512, 0, stream>>>(frag, hG, x, Whx, bh);
    y_kernel<<<(BATCH * OUTD + 255) / 256, 256, 0, stream>>>(hG, Wyh, by, out);
}

// Round 16
// 1252.317 us; speedup vs baseline: 4.8542x; 1.0235x over previous
//
#include <hip/hip_runtime.h>

// VanillaRNN: BATCH=1024, SEQ=512, HID=512, OUT=10
// h <- tanh(W_hh @ h + W_hx x_t + b_h), 512 steps, then y = W_yh h + b_y.
//
// Round 20 = revert to the R13 champion (1208us), the session's best.
// Ledger: R13's pipe-duty interleave (+5% over R4) is the only confirmed
// win. Falsified: W-from-global (R5), cross-CU M-split (R9), 1-wave ILP
// (R10), dataflow flags (R11), LDS-funded read-ahead (R12/R14: spill/null),
// AGPR pinning (R15/R16: toolchain-unsafe), wave desync (R19: clean null).
// Structure: 64 WGs x 8 waves, W CU-resident (Wr 192 regs + WL 128KB LDS),
// single HB buffer + 2 barriers, interleaved kk order spreading the 4
// LDS-W chunks evenly through the schedule:
//   ord = {12,0,1,2, 13,3,4,5, 14,6,7,8, 15,9,10,11}
// Practical floor: DS ~3100cyc + MFMA ~2480cyc per CU-step run ~half
// overlapped (5660cyc measured); every register-based pipelining lever
// hits the 256-reg/wave wall that W-residency creates.
//
// ws: [0,1MB) hG (final h, frag-blocked) | [2MB,2.5MB) W A-frags.

#define BATCH 1024
#define SEQT  512
#define HID   512
#define OUTD  10
#define KR    12   // kk-blocks (of K=32) in registers: K=384
#define NKK   16

typedef _Float16 f16;
typedef _Float16 f16x8 __attribute__((ext_vector_type(8)));
typedef _Float16 f16x4 __attribute__((ext_vector_type(4)));
typedef float    f32x4 __attribute__((ext_vector_type(4)));

// W_hh fp32 [H][H] -> fp16 A-fragment layout:
// entry ((g*4+mt)*16+kk)*64+lane = f16x8 of A[m][k],
// m = g*64+mt*16+(lane&15), k = kk*32+((lane>>4)&3)*8+j.
__global__ void wconv_kernel(const float* __restrict__ Whh, f16* __restrict__ frag) {
    int id = blockIdx.x * blockDim.x + threadIdx.x;   // 0..32767
    int lane = id & 63;
    int kk   = (id >> 6) & 15;
    int mt   = (id >> 10) & 3;
    int g    = id >> 12;
    int m = g * 64 + mt * 16 + (lane & 15);
    int k = kk * 32 + ((lane >> 4) & 3) * 8;
    const float* src = Whh + (size_t)m * HID + k;
    f16x8 v;
#pragma unroll
    for (int j = 0; j < 8; ++j) v[j] = (f16)src[j];
    *(f16x8*)(frag + (size_t)id * 8) = v;
}

__device__ __forceinline__ float fast_tanh(float v) {
    v = fminf(fmaxf(v, -15.f), 15.f);
    float e = __expf(2.f * v);
    return (e - 1.f) * __builtin_amdgcn_rcpf(e + 1.f);
}

__global__ __launch_bounds__(512)
__attribute__((amdgpu_waves_per_eu(2, 2)))
void rnn_cu(
    const f16* __restrict__ frag,   // W_hh A-frags (all 16 kk-blocks)
    f16* __restrict__ hG,           // final h, frag-blocked [64][16][64][8]
    const float* __restrict__ x,    // [B][T]
    const float* __restrict__ Whx,  // [H]
    const float* __restrict__ bh)   // [H]
{
    // HB first: its ds offsets (<16 KB) fit the 16-bit imm with lane-only base.
    __shared__ f16 HB[8192];                    // h, B-frag layout, 16 KB
    __shared__ f16 WL[65536];                   // W A-frags kk 12..15, 128 KB

    const int tid  = threadIdx.x;
    const int w    = tid >> 6;       // wave = row-group of 64 rows
    const int lane = tid & 63;
    const int n    = lane & 15;      // batch col within group
    const int q    = lane >> 4;
    const int bg   = blockIdx.x;     // batch group: cols [bg*16, +16)

    // ---- h(0) = 0 ----
    {
        f16x8 z;
#pragma unroll
        for (int j = 0; j < 8; ++j) z[j] = (f16)0.f;
        *(f16x8*)&HB[tid * 16]     = z;
        *(f16x8*)&HB[tid * 16 + 8] = z;
    }

    const f16x8* A = (const f16x8*)frag;

    // ---- LDS W portion: wave w stages its (mt, kk 12..15) frags ----
#pragma unroll
    for (int mt = 0; mt < 4; ++mt)
#pragma unroll
        for (int kkl = 0; kkl < 4; ++kkl) {
            int e = ((w * 4 + mt) * 4 + kkl) * 64 + lane;
            *(f16x8*)&WL[e * 8] = A[((w * 4 + mt) * 16 + (KR + kkl)) * 64 + lane];
        }

    // ---- register W portion: kk 0..11, kk-major, static indices ----
    f16x8 Wr[KR * 4];
#pragma unroll
    for (int kk = 0; kk < KR; ++kk)
#pragma unroll
        for (int mt = 0; mt < 4; ++mt)
            Wr[kk * 4 + mt] = A[((w * 4 + mt) * 16 + kk) * 64 + lane];

    __syncthreads();

    const int b = bg * 16 + n;
    const float* xp = x + (size_t)b * SEQT;

#pragma unroll 1
    for (int s = 0; s < SEQT; ++s) {
        float xv = xp[s];

        f32x4 acc[4] = {{0,0,0,0},{0,0,0,0},{0,0,0,0},{0,0,0,0}};

        // ---- interleaved schedule: one LDS-W block per 4-slot chunk ----
        // t%4==0 -> tail block kk=12+(t>>2) (W from WL: 4 reads + 1 h read)
        // else   -> reg block rb=t-1-(t>>2)  (W from Wr: 1 h read)
#pragma unroll
        for (int t = 0; t < NKK; ++t) {
            constexpr int ord[NKK] = {12, 0, 1, 2, 13, 3, 4, 5,
                                      14, 6, 7, 8, 15, 9, 10, 11};
            const int kb = ord[t];
            f16x8 bf = *(const f16x8*)&HB[(kb * 64 + lane) * 8];
            if ((t & 3) == 0) {
                const int kkl = t >> 2;
#pragma unroll
                for (int mt = 0; mt < 4; ++mt) {
                    f16x8 a = *(const f16x8*)&WL[(((w * 4 + mt) * 4 + kkl) * 64 + lane) * 8];
                    acc[mt] = __builtin_amdgcn_mfma_f32_16x16x32_f16(
                        a, bf, acc[mt], 0, 0, 0);
                }
            } else {
                const int rb = t - 1 - (t >> 2);
#pragma unroll
                for (int mt = 0; mt < 4; ++mt)
                    acc[mt] = __builtin_amdgcn_mfma_f32_16x16x32_f16(
                        Wr[rb * 4 + mt], bf, acc[mt], 0, 0, 0);
            }
        }

        __syncthreads();   // all reads of h(s) done before in-place overwrite

        // Block loop-invariant hoisting of Whx/bh (would cost 32 VGPRs and
        // push past the 256 budget -> spill).
        const float* wbp = Whx;
        const float* bbp = bh;
        asm volatile("" : "+v"(wbp), "+v"(bbp));

        // ---- epilogue: tanh, write h(s+1) in B-frag layout ----
        // C layout: col n = lane&15, row m = w*64 + mt*16 + q*4 + r.
#pragma unroll
        for (int mt = 0; mt < 4; ++mt) {
            int m0 = w * 64 + mt * 16 + q * 4;
            f32x4 whx4 = *(const f32x4*)(wbp + m0);
            f32x4 bh4  = *(const f32x4*)(bbp + m0);
            f16x4 hv;
#pragma unroll
            for (int r = 0; r < 4; ++r) {
                float pre = acc[mt][r] + whx4[r] * xv + bh4[r];
                hv[r] = (f16)fast_tanh(pre);
            }
            int kkd = w * 2 + (mt >> 1);
            int q2  = (mt & 1) * 2 + (q >> 1);
            int j0  = (q & 1) * 4;
            int off = (kkd * 64 + q2 * 16 + n) * 8 + j0;
            if (s < SEQT - 1) {
                *(f16x4*)&HB[off] = hv;
            } else {
                *(f16x4*)(hG + (size_t)(((bg * 16 + kkd) * 64 + q2 * 16 + n) * 8 + j0)) = hv;
            }
        }

        __syncthreads();   // h(s+1) complete before next step's reads
    }
}

// out[b][o] = by[o] + sum_k Wyh[o][k] * h[b][k], h in frag-blocked layout.
__global__ __launch_bounds__(256) void y_kernel(
    const f16* __restrict__ h, const float* __restrict__ Wyh,
    const float* __restrict__ by, float* __restrict__ out)
{
    int id = blockIdx.x * blockDim.x + threadIdx.x;
    if (id >= BATCH * OUTD) return;
    int b = id / OUTD, o = id % OUTD;
    int bg = b >> 4, n = b & 15;
    const float* wrow = Wyh + (size_t)o * HID;
    float s = by[o];
    for (int kk = 0; kk < 16; ++kk)
#pragma unroll
        for (int q2 = 0; q2 < 4; ++q2) {
            f16x8 hv = *(const f16x8*)(h + (size_t)((bg * 16 + kk) * 64 + q2 * 16 + n) * 8);
            const float* wp = wrow + kk * 32 + q2 * 8;
#pragma unroll
            for (int j = 0; j < 8; ++j) s += wp[j] * (float)hv[j];
        }
    out[id] = s;
}

extern "C" void kernel_launch(void* const* d_in, const int* in_sizes, int n_in,
                              void* d_out, int out_size, void* d_ws, size_t ws_size,
                              hipStream_t stream) {
    const float* x   = (const float*)d_in[0];
    const float* Whx = (const float*)d_in[1];
    const float* Whh = (const float*)d_in[2];
    const float* Wyh = (const float*)d_in[3];
    const float* bh  = (const float*)d_in[4];
    const float* by  = (const float*)d_in[5];
    float* out = (float*)d_out;

    char* ws   = (char*)d_ws;
    f16*  hG   = (f16*)ws;                       // 1 MB
    f16*  frag = (f16*)(ws + (2 << 20));         // 512 KB

    wconv_kernel<<<128, 256, 0, stream>>>(Whh, frag);
    rnn_cu<<<64, 512, 0, stream>>>(frag, hG, x, Whx, bh);
    y_kernel<<<(BATCH * OUTD + 255) / 256, 256, 0, stream>>>(hG, Wyh, by, out);
}